// Round 5
// baseline (539.637 us; speedup 1.0000x reference)
//
#include <hip/hip_runtime.h>
#include <hip/hip_bf16.h>

typedef __attribute__((ext_vector_type(8))) short short8;
typedef __attribute__((ext_vector_type(4))) float f32x4;
typedef __attribute__((ext_vector_type(4))) int i32x4;
typedef __attribute__((ext_vector_type(4))) unsigned u32x4;

#define NTOK 512
#define NEXP 16
#define TOPK 4
#define HD   2880
#define ID   2880
#define N1   5760   // 2*I
#define NGRP 90     // 32-value groups per row
#define NKT  45     // HD/64 K-steps

__device__ __forceinline__ unsigned perm(unsigned hi, unsigned lo, unsigned sel) {
  return __builtin_amdgcn_perm(hi, lo, sel);
}

// ---------------- perm-LUT MXFP4 dequant (bit-exact bf16, scale folded) ----------------
__device__ __forceinline__ u32x4 dq_word4(unsigned p, unsigned hbl, unsigned hbh,
                                          unsigned lbl, unsigned lbh) {
  unsigned ph = p >> 4;
  unsigned il = p  & 0x07070707u, sl = p  & 0x08080808u;
  unsigned ih = ph & 0x07070707u, sh = ph & 0x08080808u;
  unsigned hbL = perm(hbh, hbl, il) | (sl << 4);
  unsigned lbL = perm(lbh, lbl, il);
  unsigned hbH = perm(hbh, hbl, ih) | (sh << 4);
  unsigned lbH = perm(lbh, lbl, ih);
  unsigned mL01 = perm(hbL, lbL, 0x05010400u);
  unsigned mL23 = perm(hbL, lbL, 0x07030602u);
  unsigned mH01 = perm(hbH, lbH, 0x05010400u);
  unsigned mH23 = perm(hbH, lbH, 0x07030602u);
  u32x4 w;
  w.x = perm(mH01, mL01, 0x05040100u);
  w.y = perm(mH01, mL01, 0x07060302u);
  w.z = perm(mH23, mL23, 0x05040100u);
  w.w = perm(mH23, mL23, 0x07060302u);
  return w;
}

__device__ __forceinline__ void dq_store(i32x4 q0, i32x4 q1, i32x4 q2, i32x4 q3, int sc,
                                         char* d0, char* d1, char* d2, char* d3) {
  unsigned m7 = (unsigned)((127 - sc) << 7);          // sc in [118,127]
  unsigned mm = m7 | (m7 << 16);
  unsigned e10 = (0x3F00u - m7) << 16;                // entry0 stays exact 0
  unsigned e32 = 0x3FC03F80u - mm;
  unsigned e54 = 0x40404000u - mm;
  unsigned e76 = 0x40C04080u - mm;
  unsigned hbl = perm(e32, e10, 0x07050301u);
  unsigned hbh = perm(e76, e54, 0x07050301u);
  unsigned lbl = perm(e32, e10, 0x06040200u);
  unsigned lbh = perm(e76, e54, 0x06040200u);
  unsigned pk;
  pk = (unsigned)q0.x | ((unsigned)q0.y << 8) | ((unsigned)q0.z << 16) | ((unsigned)q0.w << 24);
  *(u32x4*)d0 = dq_word4(pk, hbl, hbh, lbl, lbh);
  pk = (unsigned)q1.x | ((unsigned)q1.y << 8) | ((unsigned)q1.z << 16) | ((unsigned)q1.w << 24);
  *(u32x4*)d1 = dq_word4(pk, hbl, hbh, lbl, lbh);
  pk = (unsigned)q2.x | ((unsigned)q2.y << 8) | ((unsigned)q2.z << 16) | ((unsigned)q2.w << 24);
  *(u32x4*)d2 = dq_word4(pk, hbl, hbh, lbl, lbh);
  pk = (unsigned)q3.x | ((unsigned)q3.y << 8) | ((unsigned)q3.z << 16) | ((unsigned)q3.w << 24);
  *(u32x4*)d3 = dq_word4(pk, hbl, hbh, lbl, lbh);
}

// ---------------- RMSNorm (also zeroes cnt; runs before router on the stream) ----------------
__global__ __launch_bounds__(256)
void rmsnorm_k(const float* __restrict__ x, const float* __restrict__ nsc,
               float* __restrict__ tf, __hip_bfloat16* __restrict__ tb,
               int* __restrict__ cnt)
{
  int t = blockIdx.x;
  if (t == 0 && threadIdx.x < NEXP) cnt[threadIdx.x] = 0;
  const float* xr = x + (size_t)t * HD;
  float s = 0.f;
  for (int i = threadIdx.x; i < HD; i += 256) { float v = xr[i]; s += v * v; }
#pragma unroll
  for (int o = 32; o > 0; o >>= 1) s += __shfl_down(s, o);
  __shared__ float red[4];
  if ((threadIdx.x & 63) == 0) red[threadIdx.x >> 6] = s;
  __syncthreads();
  float tot = red[0] + red[1] + red[2] + red[3];
  float rinv = rsqrtf(tot / (float)HD + 1e-5f);
  for (int i = threadIdx.x; i < HD; i += 256) {
    float v = xr[i] * rinv * nsc[i];
    tf[(size_t)t * HD + i] = v;
    tb[(size_t)t * HD + i] = __float2bfloat16(v);
  }
}

// ---------------- Router ----------------
__global__ __launch_bounds__(256)
void router_k(const float* __restrict__ tf, const float* __restrict__ gw,
              const float* __restrict__ gb, float* __restrict__ wpair,
              int* __restrict__ cnt, int* __restrict__ tok_list, int* __restrict__ pair_list)
{
  int t = blockIdx.x;
  int tid = threadIdx.x;
  int e = tid >> 4, l16 = tid & 15;
  const float* tr = tf + (size_t)t * HD;
  float s = 0.f;
  for (int i = l16; i < HD; i += 16) s += tr[i] * gw[e * HD + i];
#pragma unroll
  for (int o = 1; o < 16; o <<= 1) s += __shfl_xor(s, o);
  __shared__ float logits[NEXP];
  if (l16 == 0) logits[e] = s + gb[e];
  __syncthreads();
  if (tid == 0) {
    float v[NEXP];
#pragma unroll
    for (int i = 0; i < NEXP; ++i) v[i] = logits[i];
    int idx[TOPK]; float val[TOPK];
#pragma unroll
    for (int k = 0; k < TOPK; ++k) {
      int bi = 0; float bv = -1e30f;
      for (int i = 0; i < NEXP; ++i) if (v[i] > bv) { bv = v[i]; bi = i; }
      idx[k] = bi; val[k] = bv; v[bi] = -1e30f;
    }
    float mx = val[0], sum = 0.f, w[TOPK];
#pragma unroll
    for (int k = 0; k < TOPK; ++k) { w[k] = __expf(val[k] - mx); sum += w[k]; }
#pragma unroll
    for (int k = 0; k < TOPK; ++k) {
      float wk = w[k] / sum;
      int ee = idx[k];
      int slot = atomicAdd(&cnt[ee], 1);
      tok_list[ee * NTOK + slot]  = t;
      pair_list[ee * NTOK + slot] = t * TOPK + k;
      wpair[t * TOPK + k] = wk;
    }
  }
}

// ---------------- helpers for the GEMM pipeline ----------------
__device__ __forceinline__ void stage_write(char* Ab, char* Bb,
    const int* awoff, const int* bdoff,
    i32x4 a0, i32x4 a1, i32x4 a2, i32x4 a3,
    i32x4 q0, i32x4 q1, i32x4 q2, i32x4 q3, int sc)
{
  *(i32x4*)(Ab + awoff[0]) = a0;
  *(i32x4*)(Ab + awoff[1]) = a1;
  *(i32x4*)(Ab + awoff[2]) = a2;
  *(i32x4*)(Ab + awoff[3]) = a3;
  dq_store(q0, q1, q2, q3, sc,
           Bb + bdoff[0], Bb + bdoff[1], Bb + bdoff[2], Bb + bdoff[3]);
}

__device__ __forceinline__ void mfma_phase(const char* Ab, const char* Bb,
    const int (*aoff)[2], const int (*boff)[2], f32x4 (*acc)[4])
{
  __builtin_amdgcn_s_setprio(1);
#pragma unroll
  for (int kk = 0; kk < 2; ++kk) {
    short8 af[4], bf[4];
#pragma unroll
    for (int f = 0; f < 4; ++f) {
      af[f] = *(const short8*)(Ab + aoff[f][kk]);
      bf[f] = *(const short8*)(Bb + boff[f][kk]);
    }
#pragma unroll
    for (int ma = 0; ma < 4; ++ma)
#pragma unroll
      for (int nb = 0; nb < 4; ++nb)
        acc[ma][nb] = __builtin_amdgcn_mfma_f32_16x16x32_bf16(af[ma], bf[nb], acc[ma][nb], 0, 0, 0);
  }
  __builtin_amdgcn_s_setprio(0);
}

#define LOAD_T(aa0, aa1, aa2, aa3, qq0, qq1, qq2, qq3, ssc, tt) do { \
    const i32x4* ap_ = (const i32x4*)(agp + (tt) * 128); \
    aa0 = ap_[0]; aa1 = ap_[1]; aa2 = ap_[2]; aa3 = ap_[3]; \
    const int gn_ = (tt) * 2 + bgrp; \
    const i32x4* bp_ = (const i32x4*)(bptr + gn_ * 16); \
    qq0 = bp_[0]; qq1 = bp_[1]; qq2 = bp_[2]; qq3 = bp_[3]; \
    ssc = Bscl[brbase + gn_]; } while (0)

#define SYNC_LGKM do { asm volatile("s_waitcnt lgkmcnt(0)" ::: "memory"); \
    __builtin_amdgcn_sched_barrier(0); __builtin_amdgcn_s_barrier(); \
    __builtin_amdgcn_sched_barrier(0); } while (0)
#define SYNC_PLAIN do { __builtin_amdgcn_sched_barrier(0); __builtin_amdgcn_s_barrier(); \
    __builtin_amdgcn_sched_barrier(0); } while (0)

// ---------------- Grouped GEMM: ping-pong reg-staged pipeline (cover ~1.3 iters),
// ---------------- raw barriers, all VMEM waits compiler-managed ----------------
template<int STAGE>
__global__ __launch_bounds__(256)
void moe_gemm(const __hip_bfloat16* __restrict__ Asrc,
              const int* __restrict__ Bblk, const int* __restrict__ Bscl,
              const float* __restrict__ Bbias,
              const int* __restrict__ cnt,
              const int* __restrict__ tok_list, const int* __restrict__ pair_list,
              __hip_bfloat16* __restrict__ h_out, float* __restrict__ o_out)
{
  constexpr int NDIM = (STAGE == 1) ? N1 : HD;
  const int e  = blockIdx.z;
  const int ne = cnt[e];
  const int m0 = blockIdx.y * 128;
  if (m0 >= ne) return;
  const int n0 = blockIdx.x * 128;
  const int tid = threadIdx.x;
  const int wave = tid >> 6, lane = tid & 63;

  __shared__ __align__(16) char Abuf[2][16384];  // [128 rows][128 B] bf16, XOR-swizzled
  __shared__ __align__(16) char Bbuf[2][16384];

  const int* glist = (STAGE == 1 ? tok_list : pair_list) + e * NTOK;
  const int* plist = pair_list + e * NTOK;

  // --- A reg-staging: thread -> (row, 64B-half). Swizzle applied on WRITE side. ---
  const int arow = tid >> 1, akc = tid & 1;
  int aslot = m0 + arow; if (aslot > ne - 1) aslot = ne - 1;
  const char* agp = (const char*)Asrc + (size_t)glist[aslot] * (HD * 2) + akc * 64;
  int awoff[4];
#pragma unroll
  for (int c = 0; c < 4; ++c)
    awoff[c] = arow * 128 + ((akc * 64 + c * 16) ^ ((arow & 7) << 4));

  // --- B staging: thread -> (row, group-half); clamped unconditional loads ---
  const int brow = tid >> 1, bgrp = tid & 1;
  int nidx = n0 + brow; if (nidx >= NDIM) nidx = NDIM - 1;
  const size_t brbase = (size_t)(e * NDIM + nidx) * NGRP;
  const int* bptr = Bblk + brbase * 16;
  int bdoff[4];
#pragma unroll
  for (int c = 0; c < 4; ++c) {
    int chunk = (bgrp * 4 + c) ^ (brow & 7);
    bdoff[c] = brow * 128 + chunk * 16;
  }

  // --- MFMA fragment LDS read offsets (k-independent) ---
  const int l15 = lane & 15, l4 = lane >> 4;
  const int wm = (wave >> 1) * 64, wn = (wave & 1) * 64;
  int aoff[4][2], boff[4][2];
#pragma unroll
  for (int f = 0; f < 4; ++f) {
    int ra = wm + f * 16 + l15;
    int rb = wn + f * 16 + l15;
#pragma unroll
    for (int kk = 0; kk < 2; ++kk) {
      aoff[f][kk] = ra * 128 + ((kk * 64 + l4 * 16) ^ ((ra & 7) << 4));
      boff[f][kk] = rb * 128 + ((kk * 64 + l4 * 16) ^ ((rb & 7) << 4));
    }
  }

  f32x4 zero = {0.f, 0.f, 0.f, 0.f};
  f32x4 acc[4][4];
#pragma unroll
  for (int a = 0; a < 4; ++a)
#pragma unroll
    for (int b = 0; b < 4; ++b) acc[a][b] = zero;

  // --- two staged register sets (static names; even iters use E, odd use O) ---
  i32x4 aE0, aE1, aE2, aE3, qE0, qE1, qE2, qE3; int scE;
  i32x4 aO0, aO1, aO2, aO3, qO0, qO1, qO2, qO3; int scO;

  // --- prologue: tile0 -> buf0 directly; tile1 -> E; tile2 -> O ---
  LOAD_T(aE0, aE1, aE2, aE3, qE0, qE1, qE2, qE3, scE, 0);
  stage_write(Abuf[0], Bbuf[0], awoff, bdoff, aE0, aE1, aE2, aE3, qE0, qE1, qE2, qE3, scE);
  LOAD_T(aE0, aE1, aE2, aE3, qE0, qE1, qE2, qE3, scE, 1);
  LOAD_T(aO0, aO1, aO2, aO3, qO0, qO1, qO2, qO3, scO, 2);
  SYNC_LGKM;

  // --- steady state: tp = 0..20, guard-free (tiles 3..44 loaded here) ---
  for (int tp = 0; tp < 21; ++tp) {
    const int t = 2 * tp;
    // even iter t: W: E(tile t+1) -> buf1 ; I: tile t+3 -> E ; C: buf0 (tile t)
    stage_write(Abuf[1], Bbuf[1], awoff, bdoff, aE0, aE1, aE2, aE3, qE0, qE1, qE2, qE3, scE);
    LOAD_T(aE0, aE1, aE2, aE3, qE0, qE1, qE2, qE3, scE, t + 3);
    SYNC_LGKM;
    mfma_phase(Abuf[0], Bbuf[0], aoff, boff, acc);
    SYNC_PLAIN;
    // odd iter t+1: W: O(tile t+2) -> buf0 ; I: tile t+4 -> O ; C: buf1 (tile t+1)
    stage_write(Abuf[0], Bbuf[0], awoff, bdoff, aO0, aO1, aO2, aO3, qO0, qO1, qO2, qO3, scO);
    LOAD_T(aO0, aO1, aO2, aO3, qO0, qO1, qO2, qO3, scO, t + 4);
    SYNC_LGKM;
    mfma_phase(Abuf[1], Bbuf[1], aoff, boff, acc);
    SYNC_PLAIN;
  }

  // --- last pair t=42,43 (no more loads) ---
  stage_write(Abuf[1], Bbuf[1], awoff, bdoff, aE0, aE1, aE2, aE3, qE0, qE1, qE2, qE3, scE); // tile 43
  SYNC_LGKM;
  mfma_phase(Abuf[0], Bbuf[0], aoff, boff, acc);  // tile 42
  SYNC_PLAIN;
  stage_write(Abuf[0], Bbuf[0], awoff, bdoff, aO0, aO1, aO2, aO3, qO0, qO1, qO2, qO3, scO); // tile 44
  SYNC_LGKM;
  mfma_phase(Abuf[1], Bbuf[1], aoff, boff, acc);  // tile 43
  SYNC_PLAIN;
  // --- tail: tile 44 in buf0 ---
  mfma_phase(Abuf[0], Bbuf[0], aoff, boff, acc);

  // --- epilogue ---
  if (STAGE == 1) {
#pragma unroll
    for (int ma = 0; ma < 4; ++ma) {
#pragma unroll
      for (int nb = 0; nb < 4; ++nb) {
        int ncol = n0 + wn + nb * 16 + l15;
        float bias = Bbias[e * NDIM + ncol];
#pragma unroll
        for (int j = 0; j < 4; ++j) {
          float u  = acc[ma][nb][j] + bias;
          float up = __shfl_xor(u, 1);
          int slot = m0 + wm + ma * 16 + l4 * 4 + j;
          if (!(lane & 1) && slot < ne) {
            float g  = fminf(u, 7.f);
            float lv = fminf(fmaxf(up, -7.f), 7.f);
            float hv = g / (1.f + __expf(-1.702f * g)) * (lv + 1.f);
            h_out[(size_t)plist[slot] * ID + (ncol >> 1)] = __float2bfloat16(hv);
          }
        }
      }
    }
  } else {
#pragma unroll
    for (int ma = 0; ma < 4; ++ma) {
#pragma unroll
      for (int nb = 0; nb < 4; ++nb) {
        int ncol = n0 + wn + nb * 16 + l15;
        if (ncol < NDIM) {
          float bias = Bbias[e * NDIM + ncol];
#pragma unroll
          for (int j = 0; j < 4; ++j) {
            int slot = m0 + wm + ma * 16 + l4 * 4 + j;
            if (slot < ne)
              o_out[(size_t)plist[slot] * HD + ncol] = acc[ma][nb][j] + bias;
          }
        }
      }
    }
  }
}

// ---------------- Final combine ----------------
__global__ __launch_bounds__(256)
void final_k(const float* __restrict__ x, const float* __restrict__ obuf,
             const float* __restrict__ wpair, float* __restrict__ out)
{
  int t = blockIdx.x;
  float w0 = wpair[t * 4 + 0], w1 = wpair[t * 4 + 1];
  float w2 = wpair[t * 4 + 2], w3 = wpair[t * 4 + 3];
  const float* o0 = obuf + (size_t)(t * 4) * HD;
  for (int i = threadIdx.x; i < HD; i += 256) {
    float r = x[(size_t)t * HD + i]
            + w0 * o0[i] + w1 * o0[HD + i] + w2 * o0[2 * HD + i] + w3 * o0[3 * HD + i];
    out[(size_t)t * HD + i] = r;
  }
}

extern "C" void kernel_launch(void* const* d_in, const int* in_sizes, int n_in,
                              void* d_out, int out_size, void* d_ws, size_t ws_size,
                              hipStream_t stream)
{
  const float* x    = (const float*)d_in[0];
  const float* nsc  = (const float*)d_in[1];
  const float* gw   = (const float*)d_in[2];
  const float* gb   = (const float*)d_in[3];
  const int*   b1   = (const int*)d_in[4];
  const int*   s1   = (const int*)d_in[5];
  const float* bia1 = (const float*)d_in[6];
  const int*   b2   = (const int*)d_in[7];
  const int*   s2   = (const int*)d_in[8];
  const float* bia2 = (const float*)d_in[9];
  float* out = (float*)d_out;

  char* ws = (char*)d_ws;
  size_t off = 0;
  auto alloc = [&](size_t bytes) {
    char* p = ws + off;
    off = (off + bytes + 255) & ~(size_t)255;
    return p;
  };
  float*           tf    = (float*)alloc((size_t)NTOK * HD * 4);
  __hip_bfloat16*  tb    = (__hip_bfloat16*)alloc((size_t)NTOK * HD * 2);
  __hip_bfloat16*  hbuf  = (__hip_bfloat16*)alloc((size_t)NTOK * TOPK * ID * 2);
  float*           obuf  = (float*)alloc((size_t)NTOK * TOPK * HD * 4);
  float*           wpair = (float*)alloc(NTOK * TOPK * 4);
  int*             cnt   = (int*)alloc(64);
  int*             tokl  = (int*)alloc(NEXP * NTOK * 4);
  int*             pairl = (int*)alloc(NEXP * NTOK * 4);

  rmsnorm_k<<<NTOK, 256, 0, stream>>>(x, nsc, tf, tb, cnt);
  router_k<<<NTOK, 256, 0, stream>>>(tf, gw, gb, wpair, cnt, tokl, pairl);
  moe_gemm<1><<<dim3(N1 / 128, 4, NEXP), 256, 0, stream>>>(tb, b1, s1, bia1, cnt, tokl, pairl, hbuf, nullptr);
  moe_gemm<2><<<dim3((HD + 127) / 128, 4, NEXP), 256, 0, stream>>>(hbuf, b2, s2, bia2, cnt, tokl, pairl, nullptr, obuf);
  final_k<<<NTOK, 256, 0, stream>>>(x, obuf, wpair, out);
}